// Round 8
// baseline (117.387 us; speedup 1.0000x reference)
//
#include <hip/hip_runtime.h>

// Problem constants (from reference setup_inputs) — all tensors are fp32.
#define BATCH 16
#define NVEC 1024
#define NDIM 64
#define NHID 32
#define NW   10
#define NCLS 10
#define NOFF 11      // diag + 10 power-of-2 offsets (chord mask: 11 nnz/row)
#define WPAD 12      // padded weights-per-row so k_chain reads 3x float4
#define W2PAD 36     // padded row length for the staged-W2 LDS cache
#define NROW 8       // n-rows per k_weights block (4 per thread, 2 waves)
#define NSLOT 64     // staged W2T rows: [0,24) u ({32,64,128,256,512}+[0,8))
#define NCHUNK2 32   // k_chain: 32 chunks of 2 dims (512 blocks, 2/CU)

// ---------------------------------------------------------------------------
// Kernel 1: all sparse chord weights, all 10 layers.  [body = round-7 rolled
// version, benched equal to all unrolled variants]  + NEW: block (0,0)
// initializes out = bias so k_chain can atomicAdd into it (k_finish is gone
// — each kernel dispatch costs ~8-10 µs of launch gap in this harness).
//
// Session journal:
//  * rounds 4-7: four k_weights restructures (rows/thread, block size,
//    VGPR caps, I$ footprint) ALL neutral -> k_weights is NOT the ~40 µs
//    the early ledger claimed; residual time is inter-dispatch overhead.
//  * round-2 post-mortem: NEVER fuse cross-block reduction via
//    __threadfence — whole-L2 writeback/inv per block (+50 µs). Plain
//    device-scope atomicAdd into out has no such fence.
// ---------------------------------------------------------------------------
__global__ __launch_bounds__(128, 2) void k_weights(
    const float* __restrict__ data,   // [B][NVEC][NDIM]
    const float* __restrict__ fW1,    // [NW][NDIM][NHID]
    const float* __restrict__ fb1,    // [NW][NHID]
    const float* __restrict__ fW2,    // [NW][NHID][NVEC]
    const float* __restrict__ fb2,    // [NW][NVEC]
    float* __restrict__ Wsp,          // [NW][B][NVEC][WPAD]
    const float* __restrict__ bias,   // [NCLS]
    float* __restrict__ out)          // [B][NCLS]
{
    const int i = blockIdx.y;
    const int nbase = blockIdx.x * NROW;
    const int t = threadIdx.x;        // 0..127
    const int jq = t & 3;
    const int b  = (t >> 2) & 15;
    const int nl = t >> 6;            // wave index 0..1 (4 rows each)
    const int j0 = jq * 8;

    __shared__ __align__(16) float sW1[NDIM * NHID];        // [d][j], 8 KB
    __shared__ float sb1[NHID];
    __shared__ __align__(16) float sW2r[NSLOT * W2PAD];     // 9.2 KB
    __shared__ float sb2[NSLOT];                            // fb2 at slots
    __shared__ __align__(16) float rws[NROW * BATCH * WPAD];// 6 KB

    if (blockIdx.x == 0 && i == 0) {
        // init out = bias (k_chain atomicAdds on top; stream order + kernel
        // boundary flush make this visible to k_chain's atomics)
        for (int k = t; k < BATCH * NCLS; k += 128) out[k] = bias[k % NCLS];
    }

    {
        const float4* w1v = (const float4*)(fW1 + (size_t)i * NDIM * NHID);
        float4* s4 = (float4*)sW1;
        for (int k = t; k < NDIM * NHID / 4; k += 128) s4[k] = w1v[k];
        if (t < NHID) sb1[t] = fb1[i * NHID + t];

        // stage the 64 needed fW2 columns (rows of W2^T) into LDS.
        const int s  = t & 63;
        const int j2 = t >> 6;        // 0..1
        int k = (s < 24) ? s : ((32 << ((s - 24) >> 3)) + ((s - 24) & 7));
        int m = (nbase + k) & (NVEC - 1);
        const float* w2 = fW2 + (size_t)i * NHID * NVEC + m;
        #pragma unroll 1
        for (int jj = 0; jj < 16; ++jj)
            sW2r[s * W2PAD + (j2 + jj * 2)] = w2[(size_t)(j2 + jj * 2) * NVEC];
        if (t < NSLOT) sb2[s] = fb2[(size_t)i * NVEC + m];

        // zero the WPAD pad slot so Wsp never carries stale-LDS bits
        rws[t * WPAD + (WPAD - 1)] = 0.0f;
    }
    __syncthreads();

    float h[4][8];
    #pragma unroll
    for (int r = 0; r < 4; ++r)
        #pragma unroll
        for (int jj = 0; jj < 8; ++jj) h[r][jj] = sb1[j0 + jj];

    const int n0 = nbase + nl * 4;    // 4 consecutive rows -> one base ptr
    const float4* rowp = (const float4*)(data + ((size_t)(b * NVEC) + n0) * NDIM);

    // rolled g-loop with 1-deep data prefetch
    float4 c0 = rowp[0], c1 = rowp[16], c2 = rowp[32], c3 = rowp[48];
    #pragma unroll 1
    for (int g = 0; g < 16; ++g) {
        const int gn = (g + 1) & 15;              // wrap: always in-bounds
        float4 p0 = rowp[gn];
        float4 p1 = rowp[16 + gn];
        float4 p2 = rowp[32 + gn];
        float4 p3 = rowp[48 + gn];
        const float as0[4] = {c0.x, c0.y, c0.z, c0.w};
        const float as1[4] = {c1.x, c1.y, c1.z, c1.w};
        const float as2[4] = {c2.x, c2.y, c2.z, c2.w};
        const float as3[4] = {c3.x, c3.y, c3.z, c3.w};
        #pragma unroll
        for (int dk = 0; dk < 4; ++dk) {
            const float4* wp = (const float4*)(&sW1[(g * 4 + dk) * NHID + j0]);
            float4 w0 = wp[0], w1 = wp[1];
            const float wf[8] = {w0.x, w0.y, w0.z, w0.w, w1.x, w1.y, w1.z, w1.w};
            #pragma unroll
            for (int jj = 0; jj < 8; ++jj) {
                h[0][jj] += as0[dk] * wf[jj];
                h[1][jj] += as1[dk] * wf[jj];
                h[2][jj] += as2[dk] * wf[jj];
                h[3][jj] += as3[dk] * wf[jj];
            }
        }
        c0 = p0; c1 = p1; c2 = p2; c3 = p3;
    }

    // exact gelu (bit-match with reference)
    #pragma unroll
    for (int r = 0; r < 4; ++r)
        #pragma unroll
        for (int jj = 0; jj < 8; ++jj) {
            float x = h[r][jj];
            h[r][jj] = 0.5f * x * (1.0f + erff(x * 0.70710678118654752f));
        }

    // sparse gather: W[n, (n+off)&1023] = h[n] . W2T[(n+off)&1023] + b2
    const int rbase = nl * 4;         // 0 or 4
    #pragma unroll 1
    for (int o = 0; o < NOFF; ++o) {
        const int off   = (o == 0) ? 0 : (1 << (o - 1));
        const int sbase = (o == 0) ? 0 : ((off <= 16) ? off : (24 + 8 * (o - 6)));
        const bool mine = (jq == (o & 3));
        #pragma unroll
        for (int r = 0; r < 4; ++r) {
            const int slot = sbase + rbase + r;
            const float4* gp = (const float4*)(sW2r + slot * W2PAD + j0);
            float4 g0 = gp[0], g1 = gp[1];
            float w = h[r][0] * g0.x + h[r][1] * g0.y + h[r][2] * g0.z + h[r][3] * g0.w
                    + h[r][4] * g1.x + h[r][5] * g1.y + h[r][6] * g1.z + h[r][7] * g1.w;
            w += __shfl_xor(w, 1, 64);    // combine jq bit 0 (DPP quad_perm)
            w += __shfl_xor(w, 2, 64);    // combine jq bit 1 (DPP quad_perm)
            if (mine)
                rws[(b * NROW + rbase + r) * WPAD + o] = w + sb2[slot];
        }
    }
    __syncthreads();

    // coalesced write-out: 128 rows x 12 floats = 384 float4
    {
        const float4* rv = (const float4*)rws;
        #pragma unroll 1
        for (int k = t; k < NROW * BATCH * 3; k += 128) {
            int row = k / 3, comp = k - row * 3;
            int bb = row >> 3, rr = row & 7;
            float4* dst = (float4*)(Wsp +
                ((size_t)(i * BATCH + bb) * NVEC + nbase + rr) * WPAD + comp * 4);
            *dst = rv[k];
        }
    }
}

// ---------------------------------------------------------------------------
// Kernel 2: FUSED 10-layer chain + final projection + atomic output.
// NEW: 512 blocks = (b, 32 chunks of 2 dims), float2 V-slice (16 KB LDS)
// -> 2 blocks/CU (the old 256-block grid capped residency at 1/CU; CUs
// idled during each layer's barrier+LDS-latency window — two independent
// barrier domains per CU hide it). Thread n owns rows n and n+512 in
// registers (offset-512 gather stays register-local). Block reduces its
// 10 class partials and atomicAdds into out (bias pre-written by
// k_weights). FP note: atomic order replaces the fixed chunk order ->
// absmax ~1e-6 instead of 0.0 (within tolerance); no fences involved.
// XCD mapping: the 32 chunk-blocks of each b land on one XCD.
// grid (512), block 512.
// ---------------------------------------------------------------------------
__global__ __launch_bounds__(512) void k_chain(
    const float* __restrict__ data,   // [B][NVEC][NDIM]
    const float* __restrict__ Wsp,    // [NW][B][NVEC][WPAD]
    const float* __restrict__ Wf,     // [NVEC*NDIM][NCLS]
    float* __restrict__ out)          // [B][NCLS]
{
    const int lin   = blockIdx.x;           // 0..511
    const int xcd   = lin & 7;
    const int slot  = lin >> 3;             // 0..63
    const int b     = (xcd << 1) | (slot >> 5);
    const int chunk = slot & 31;            // 0..31
    const int d0    = chunk * 2;
    const int n     = threadIdx.x;          // 0..511
    const int n2    = n + 512;

    __shared__ float2 bufA[NVEC];           // 8 KB
    __shared__ float2 bufB[NVEC];           // 8 KB

    float2 v0own = *(const float2*)(data + ((size_t)(b * NVEC) + n)  * NDIM + d0);
    float2 v1own = *(const float2*)(data + ((size_t)(b * NVEC) + n2) * NDIM + d0);
    bufA[n]  = v0own;
    bufA[n2] = v1own;

    // prefetch layer NW-1 weights for both rows
    const float* wbase = Wsp + (size_t)((NW - 1) * BATCH + b) * NVEC * WPAD;
    const float4* wp0 = (const float4*)(wbase + (size_t)n  * WPAD);
    const float4* wp1 = (const float4*)(wbase + (size_t)n2 * WPAD);
    float4 wa0 = wp0[0], wb0 = wp0[1], wc0 = wp0[2];
    float4 wa1 = wp1[0], wb1 = wp1[1], wc1 = wp1[2];
    __syncthreads();

    float2* cur = bufA;
    float2* nxt = bufB;

    for (int l = 0; l < NW; ++l) {
        float4 na0, nb0, nc0, na1, nb1, nc1;
        if (l < NW - 1) {   // prefetch next layer (in flight across barrier)
            const float* nbase_p = Wsp + (size_t)((NW - 2 - l) * BATCH + b) * NVEC * WPAD;
            const float4* q0 = (const float4*)(nbase_p + (size_t)n  * WPAD);
            const float4* q1 = (const float4*)(nbase_p + (size_t)n2 * WPAD);
            na0 = q0[0]; nb0 = q0[1]; nc0 = q0[2];
            na1 = q1[0]; nb1 = q1[1]; nc1 = q1[2];
        }
        const float wg0[12] = {wa0.x, wa0.y, wa0.z, wa0.w,
                               wb0.x, wb0.y, wb0.z, wb0.w,
                               wc0.x, wc0.y, wc0.z, wc0.w};
        const float wg1[12] = {wa1.x, wa1.y, wa1.z, wa1.w,
                               wb1.x, wb1.y, wb1.z, wb1.w,
                               wc1.x, wc1.y, wc1.z, wc1.w};
        // row n (diag + offsets; offset 512 comes from v1own register)
        float2 acc0;
        acc0.x = v0own.x + wg0[0] * v0own.x;
        acc0.y = v0own.y + wg0[0] * v0own.y;
        #pragma unroll
        for (int o = 1; o < NOFF; ++o) {
            int off = 1 << (o - 1);
            float2 vv = (off == 512) ? v1own : cur[(n + off) & (NVEC - 1)];
            acc0.x += wg0[o] * vv.x; acc0.y += wg0[o] * vv.y;
        }
        // row n+512 (offset 512 wraps to row n -> v0own register)
        float2 acc1;
        acc1.x = v1own.x + wg1[0] * v1own.x;
        acc1.y = v1own.y + wg1[0] * v1own.y;
        #pragma unroll
        for (int o = 1; o < NOFF; ++o) {
            int off = 1 << (o - 1);
            float2 vv = (off == 512) ? v0own : cur[(n2 + off) & (NVEC - 1)];
            acc1.x += wg1[o] * vv.x; acc1.y += wg1[o] * vv.y;
        }
        nxt[n]  = acc0;
        nxt[n2] = acc1;
        v0own = acc0;
        v1own = acc1;
        __syncthreads();
        float2* tmp = cur; cur = nxt; nxt = tmp;
        if (l < NW - 1) {
            wa0 = na0; wb0 = nb0; wc0 = nc0;
            wa1 = na1; wb1 = nb1; wc1 = nc1;
        }
    }

    // fused final projection partials for both rows — from registers.
    // Wf rows (n*NDIM+d0) and (n2*NDIM+d0), 2 dims x 10 cls = 20 floats
    // each, 16B-aligned (d0 even -> offset multiple of 4 floats).
    float p0[NCLS], p1[NCLS];
    #pragma unroll
    for (int c = 0; c < NCLS; ++c) { p0[c] = 0.0f; p1[c] = 0.0f; }
    {
        const float4* wfv0 = (const float4*)(Wf + ((size_t)(n  * NDIM + d0)) * NCLS);
        const float4* wfv1 = (const float4*)(Wf + ((size_t)(n2 * NDIM + d0)) * NCLS);
        float wf0[20], wf1[20];
        #pragma unroll
        for (int k = 0; k < 5; ++k) {
            float4 u0 = wfv0[k], u1 = wfv1[k];
            wf0[k * 4 + 0] = u0.x; wf0[k * 4 + 1] = u0.y;
            wf0[k * 4 + 2] = u0.z; wf0[k * 4 + 3] = u0.w;
            wf1[k * 4 + 0] = u1.x; wf1[k * 4 + 1] = u1.y;
            wf1[k * 4 + 2] = u1.z; wf1[k * 4 + 3] = u1.w;
        }
        const float vs0[2] = {v0own.x, v0own.y};
        const float vs1[2] = {v1own.x, v1own.y};
        #pragma unroll
        for (int d = 0; d < 2; ++d)
            #pragma unroll
            for (int cls = 0; cls < NCLS; ++cls) {
                p0[cls] += vs0[d] * wf0[d * NCLS + cls];
                p1[cls] += vs1[d] * wf1[d * NCLS + cls];
            }
    }

    // reduce 512 threads x 2 rows -> 10 values, then one atomicAdd per cls
    const int lane = n & 63, wv = n >> 6;   // 8 waves
    float* sred = (float*)nxt;              // dead buffer (post-loop)
    #pragma unroll
    for (int cls = 0; cls < NCLS; ++cls) {
        float v0 = p0[cls];
        float v1 = p1[cls];
        #pragma unroll
        for (int s = 32; s > 0; s >>= 1) {
            v0 += __shfl_down(v0, s, 64);
            v1 += __shfl_down(v1, s, 64);
        }
        if (lane == 0) {
            sred[wv * NCLS + cls]       = v0;
            sred[(wv + 8) * NCLS + cls] = v1;
        }
    }
    __syncthreads();
    if (n < NCLS) {
        float s = 0.0f;
        #pragma unroll
        for (int w = 0; w < 16; ++w) s += sred[w * NCLS + n];
        atomicAdd(out + b * NCLS + n, s);   // device-scope fp32 atomic
    }
}

// ---------------------------------------------------------------------------
extern "C" void kernel_launch(void* const* d_in, const int* in_sizes, int n_in,
                              void* d_out, int out_size, void* d_ws, size_t ws_size,
                              hipStream_t stream) {
    const float* data = (const float*)d_in[0];
    const float* fW1  = (const float*)d_in[1];
    const float* fb1  = (const float*)d_in[2];
    const float* fW2  = (const float*)d_in[3];
    const float* fb2  = (const float*)d_in[4];
    const float* fWf  = (const float*)d_in[5];
    const float* fbf  = (const float*)d_in[6];
    float* out = (float*)d_out;

    float* ws   = (float*)d_ws;
    float* Wsp  = ws;                 // NW*B*NVEC*WPAD = 1,966,080 floats

    k_weights<<<dim3(NVEC / NROW, NW), 128, 0, stream>>>(
        data, fW1, fb1, fW2, fb2, Wsp, fbf, out);
    k_chain<<<dim3(NCHUNK2 * BATCH), 512, 0, stream>>>(data, Wsp, fWf, out);
}

// Round 9
// 116.374 us; speedup vs baseline: 1.0087x; 1.0087x over previous
//
#include <hip/hip_runtime.h>

// Problem constants (from reference setup_inputs) — all tensors are fp32.
#define BATCH 16
#define NVEC 1024
#define NDIM 64
#define NHID 32
#define NW   10
#define NCLS 10
#define NOFF 11      // diag + 10 power-of-2 offsets (chord mask: 11 nnz/row)
#define WPAD 12      // padded weights-per-row so k_chain reads 3x float4
#define NCHUNK (NDIM / 4)   // 16 d-chunks in k_chain
#define W2PAD 36     // padded row length for the staged-W2 LDS cache
#define NROW 8       // n-rows per k_weights block (4 per thread, 2 waves)
#define NSLOT 64     // staged W2T rows: [0,24) u ({32,64,128,256,512}+[0,8))

// ---------------------------------------------------------------------------
// SESSION LEDGER (rounds 0-8):
//  * dur_us ≈ 84 µs harness re-poison fills (fixed; 2x 256 MiB at ~80% HBM
//    peak) + ~7 µs k_weights + ~20-25 µs k_chain + ~3 µs finish/gaps.
//  * k_weights restructures (rows/thread, block size, VGPR caps, I$
//    footprint 40KB->8KB): ALL neutral -> it sits at its pipe floor.
//  * k_chain: fence-fused reduction cost +50 µs (round 2 — whole-L2
//    writeback/inv per block on gfx950; NEVER __threadfence per-block).
//    2-barrier-domain float2 variant: neutral. Atomic-out variant: -1.
//  * Dispatch gaps measured ~2 µs (k_transpose/k_finish removal exps).
// This file = round-5 configuration, the session best (115.0 µs).
// ---------------------------------------------------------------------------
__global__ __launch_bounds__(128, 2) void k_weights(
    const float* __restrict__ data,   // [B][NVEC][NDIM]
    const float* __restrict__ fW1,    // [NW][NDIM][NHID]
    const float* __restrict__ fb1,    // [NW][NHID]
    const float* __restrict__ fW2,    // [NW][NHID][NVEC]
    const float* __restrict__ fb2,    // [NW][NVEC]
    float* __restrict__ Wsp)          // [NW][B][NVEC][WPAD]
{
    const int i = blockIdx.y;
    const int nbase = blockIdx.x * NROW;
    const int t = threadIdx.x;        // 0..127
    const int jq = t & 3;
    const int b  = (t >> 2) & 15;
    const int nl = t >> 6;            // wave index 0..1 (4 rows each)
    const int j0 = jq * 8;

    __shared__ __align__(16) float sW1[NDIM * NHID];        // [d][j], 8 KB
    __shared__ float sb1[NHID];
    __shared__ __align__(16) float sW2r[NSLOT * W2PAD];     // 9.2 KB
    __shared__ float sb2[NSLOT];                            // fb2 at slots
    __shared__ __align__(16) float rws[NROW * BATCH * WPAD];// 6 KB

    {
        const float4* w1v = (const float4*)(fW1 + (size_t)i * NDIM * NHID);
        float4* s4 = (float4*)sW1;
        for (int k = t; k < NDIM * NHID / 4; k += 128) s4[k] = w1v[k];
        if (t < NHID) sb1[t] = fb1[i * NHID + t];

        // stage the 64 needed fW2 columns (rows of W2^T) into LDS.
        const int s  = t & 63;
        const int j2 = t >> 6;        // 0..1
        int k = (s < 24) ? s : ((32 << ((s - 24) >> 3)) + ((s - 24) & 7));
        int m = (nbase + k) & (NVEC - 1);
        const float* w2 = fW2 + (size_t)i * NHID * NVEC + m;
        #pragma unroll 1
        for (int jj = 0; jj < 16; ++jj)
            sW2r[s * W2PAD + (j2 + jj * 2)] = w2[(size_t)(j2 + jj * 2) * NVEC];
        if (t < NSLOT) sb2[s] = fb2[(size_t)i * NVEC + m];

        // zero the WPAD pad slot so Wsp never carries stale-LDS bits
        rws[t * WPAD + (WPAD - 1)] = 0.0f;
    }
    __syncthreads();

    float h[4][8];
    #pragma unroll
    for (int r = 0; r < 4; ++r)
        #pragma unroll
        for (int jj = 0; jj < 8; ++jj) h[r][jj] = sb1[j0 + jj];

    const int n0 = nbase + nl * 4;    // 4 consecutive rows -> one base ptr
    const float4* rowp = (const float4*)(data + ((size_t)(b * NVEC) + n0) * NDIM);

    // rolled g-loop with 1-deep data prefetch (benched equal to unrolled)
    float4 c0 = rowp[0], c1 = rowp[16], c2 = rowp[32], c3 = rowp[48];
    #pragma unroll 1
    for (int g = 0; g < 16; ++g) {
        const int gn = (g + 1) & 15;              // wrap: always in-bounds
        float4 p0 = rowp[gn];
        float4 p1 = rowp[16 + gn];
        float4 p2 = rowp[32 + gn];
        float4 p3 = rowp[48 + gn];
        const float as0[4] = {c0.x, c0.y, c0.z, c0.w};
        const float as1[4] = {c1.x, c1.y, c1.z, c1.w};
        const float as2[4] = {c2.x, c2.y, c2.z, c2.w};
        const float as3[4] = {c3.x, c3.y, c3.z, c3.w};
        #pragma unroll
        for (int dk = 0; dk < 4; ++dk) {
            const float4* wp = (const float4*)(&sW1[(g * 4 + dk) * NHID + j0]);
            float4 w0 = wp[0], w1 = wp[1];
            const float wf[8] = {w0.x, w0.y, w0.z, w0.w, w1.x, w1.y, w1.z, w1.w};
            #pragma unroll
            for (int jj = 0; jj < 8; ++jj) {
                h[0][jj] += as0[dk] * wf[jj];
                h[1][jj] += as1[dk] * wf[jj];
                h[2][jj] += as2[dk] * wf[jj];
                h[3][jj] += as3[dk] * wf[jj];
            }
        }
        c0 = p0; c1 = p1; c2 = p2; c3 = p3;
    }

    // exact gelu (bit-match with reference)
    #pragma unroll
    for (int r = 0; r < 4; ++r)
        #pragma unroll
        for (int jj = 0; jj < 8; ++jj) {
            float x = h[r][jj];
            h[r][jj] = 0.5f * x * (1.0f + erff(x * 0.70710678118654752f));
        }

    // sparse gather: W[n, (n+off)&1023] = h[n] . W2T[(n+off)&1023] + b2
    const int rbase = nl * 4;         // 0 or 4
    #pragma unroll 1
    for (int o = 0; o < NOFF; ++o) {
        const int off   = (o == 0) ? 0 : (1 << (o - 1));
        const int sbase = (o == 0) ? 0 : ((off <= 16) ? off : (24 + 8 * (o - 6)));
        const bool mine = (jq == (o & 3));
        #pragma unroll
        for (int r = 0; r < 4; ++r) {
            const int slot = sbase + rbase + r;
            const float4* gp = (const float4*)(sW2r + slot * W2PAD + j0);
            float4 g0 = gp[0], g1 = gp[1];
            float w = h[r][0] * g0.x + h[r][1] * g0.y + h[r][2] * g0.z + h[r][3] * g0.w
                    + h[r][4] * g1.x + h[r][5] * g1.y + h[r][6] * g1.z + h[r][7] * g1.w;
            w += __shfl_xor(w, 1, 64);    // combine jq bit 0 (DPP quad_perm)
            w += __shfl_xor(w, 2, 64);    // combine jq bit 1 (DPP quad_perm)
            if (mine)
                rws[(b * NROW + rbase + r) * WPAD + o] = w + sb2[slot];
        }
    }
    __syncthreads();

    // coalesced write-out: 128 rows x 12 floats = 384 float4
    {
        const float4* rv = (const float4*)rws;
        #pragma unroll 1
        for (int k = t; k < NROW * BATCH * 3; k += 128) {
            int row = k / 3, comp = k - row * 3;
            int bb = row >> 3, rr = row & 7;
            float4* dst = (float4*)(Wsp +
                ((size_t)(i * BATCH + bb) * NVEC + nbase + rr) * WPAD + comp * 4);
            *dst = rv[k];
        }
    }
}

// ---------------------------------------------------------------------------
// Kernel 2: FUSED 10-layer chain + final-projection partials.
// Block = (b, 4-dim chunk): V[1024][4] slice in LDS. 512 threads; thread n
// owns rows n AND n+512 in registers -> the offset-512 gather is a REGISTER
// read for both rows. Cross-wave reduction mapped so sred[w] (w=0..15)
// holds bitwise the same 16 partials as the 16-wave version.
// XCD-aware mapping: all 16 chunk-blocks of a b land on one XCD (L2 reuse
// of the per-layer 48 KB Wsp slab).
// grid (256), block 512.  [round-5 exact — session best]
// ---------------------------------------------------------------------------
__global__ __launch_bounds__(512) void k_chain(
    const float* __restrict__ data,   // [B][NVEC][NDIM]
    const float* __restrict__ Wsp,    // [NW][B][NVEC][WPAD]
    const float* __restrict__ Wf,     // [NVEC*NDIM][NCLS]
    float* __restrict__ part)         // [B][NCHUNK][NCLS]
{
    const int lin   = blockIdx.x;
    const int xcd   = lin & 7;
    const int slot  = lin >> 3;             // 0..31
    const int b     = (xcd << 1) | (slot >> 4);
    const int chunk = slot & 15;
    const int d0    = chunk * 4;
    const int n     = threadIdx.x;          // 0..511
    const int n2    = n + 512;

    __shared__ float4 bufA[NVEC];
    __shared__ float4 bufB[NVEC];

    float4 v0own = *(const float4*)(data + ((size_t)(b * NVEC) + n)  * NDIM + d0);
    float4 v1own = *(const float4*)(data + ((size_t)(b * NVEC) + n2) * NDIM + d0);
    bufA[n]  = v0own;
    bufA[n2] = v1own;

    // prefetch layer NW-1 weights for both rows
    const float* wbase = Wsp + (size_t)((NW - 1) * BATCH + b) * NVEC * WPAD;
    const float4* wp0 = (const float4*)(wbase + (size_t)n  * WPAD);
    const float4* wp1 = (const float4*)(wbase + (size_t)n2 * WPAD);
    float4 wa0 = wp0[0], wb0 = wp0[1], wc0 = wp0[2];
    float4 wa1 = wp1[0], wb1 = wp1[1], wc1 = wp1[2];
    __syncthreads();

    float4* cur = bufA;
    float4* nxt = bufB;

    for (int l = 0; l < NW; ++l) {
        float4 na0, nb0, nc0, na1, nb1, nc1;
        if (l < NW - 1) {   // prefetch next layer (in flight across barrier)
            const float* nbase_p = Wsp + (size_t)((NW - 2 - l) * BATCH + b) * NVEC * WPAD;
            const float4* q0 = (const float4*)(nbase_p + (size_t)n  * WPAD);
            const float4* q1 = (const float4*)(nbase_p + (size_t)n2 * WPAD);
            na0 = q0[0]; nb0 = q0[1]; nc0 = q0[2];
            na1 = q1[0]; nb1 = q1[1]; nc1 = q1[2];
        }
        const float wg0[12] = {wa0.x, wa0.y, wa0.z, wa0.w,
                               wb0.x, wb0.y, wb0.z, wb0.w,
                               wc0.x, wc0.y, wc0.z, wc0.w};
        const float wg1[12] = {wa1.x, wa1.y, wa1.z, wa1.w,
                               wb1.x, wb1.y, wb1.z, wb1.w,
                               wc1.x, wc1.y, wc1.z, wc1.w};
        // row n (diag + offsets; offset 512 comes from v1own register)
        float4 acc0;
        acc0.x = v0own.x + wg0[0] * v0own.x;
        acc0.y = v0own.y + wg0[0] * v0own.y;
        acc0.z = v0own.z + wg0[0] * v0own.z;
        acc0.w = v0own.w + wg0[0] * v0own.w;
        #pragma unroll
        for (int o = 1; o < NOFF; ++o) {
            int off = 1 << (o - 1);
            float4 vv = (off == 512) ? v1own : cur[(n + off) & (NVEC - 1)];
            acc0.x += wg0[o] * vv.x; acc0.y += wg0[o] * vv.y;
            acc0.z += wg0[o] * vv.z; acc0.w += wg0[o] * vv.w;
        }
        // row n+512 (offset 512 wraps to row n -> v0own register)
        float4 acc1;
        acc1.x = v1own.x + wg1[0] * v1own.x;
        acc1.y = v1own.y + wg1[0] * v1own.y;
        acc1.z = v1own.z + wg1[0] * v1own.z;
        acc1.w = v1own.w + wg1[0] * v1own.w;
        #pragma unroll
        for (int o = 1; o < NOFF; ++o) {
            int off = 1 << (o - 1);
            float4 vv = (off == 512) ? v0own : cur[(n2 + off) & (NVEC - 1)];
            acc1.x += wg1[o] * vv.x; acc1.y += wg1[o] * vv.y;
            acc1.z += wg1[o] * vv.z; acc1.w += wg1[o] * vv.w;
        }
        nxt[n]  = acc0;
        nxt[n2] = acc1;
        v0own = acc0;
        v1own = acc1;
        __syncthreads();
        float4* tmp = cur; cur = nxt; nxt = tmp;
        if (l < NW - 1) {
            wa0 = na0; wb0 = nb0; wc0 = nc0;
            wa1 = na1; wb1 = nb1; wc1 = nc1;
        }
    }

    // fused final projection partials for both rows — from registers
    float p0[NCLS], p1[NCLS];
    #pragma unroll
    for (int c = 0; c < NCLS; ++c) { p0[c] = 0.0f; p1[c] = 0.0f; }
    {
        float vs0[4] = {v0own.x, v0own.y, v0own.z, v0own.w};
        float vs1[4] = {v1own.x, v1own.y, v1own.z, v1own.w};
        const float4* wfv0 = (const float4*)(Wf + ((size_t)(n  * NDIM + d0)) * NCLS);
        const float4* wfv1 = (const float4*)(Wf + ((size_t)(n2 * NDIM + d0)) * NCLS);
        float wf0[40], wf1[40];
        #pragma unroll
        for (int k = 0; k < 10; ++k) {
            float4 u0 = wfv0[k], u1 = wfv1[k];
            wf0[k * 4 + 0] = u0.x; wf0[k * 4 + 1] = u0.y;
            wf0[k * 4 + 2] = u0.z; wf0[k * 4 + 3] = u0.w;
            wf1[k * 4 + 0] = u1.x; wf1[k * 4 + 1] = u1.y;
            wf1[k * 4 + 2] = u1.z; wf1[k * 4 + 3] = u1.w;
        }
        #pragma unroll
        for (int d = 0; d < 4; ++d)
            #pragma unroll
            for (int cls = 0; cls < NCLS; ++cls) {
                p0[cls] += vs0[d] * wf0[d * NCLS + cls];
                p1[cls] += vs1[d] * wf1[d * NCLS + cls];
            }
    }

    // reduce -> 10 values; wave wv emits partials of old waves wv and wv+8
    const int lane = n & 63, wv = n >> 6;   // 8 waves
    float* sred = (float*)nxt;              // dead buffer
    #pragma unroll
    for (int cls = 0; cls < NCLS; ++cls) {
        float v0 = p0[cls];
        float v1 = p1[cls];
        #pragma unroll
        for (int s = 32; s > 0; s >>= 1) {
            v0 += __shfl_down(v0, s, 64);
            v1 += __shfl_down(v1, s, 64);
        }
        if (lane == 0) {
            sred[wv * NCLS + cls]       = v0;
            sred[(wv + 8) * NCLS + cls] = v1;
        }
    }
    __syncthreads();
    if (n < NCLS) {
        float s = 0.0f;
        #pragma unroll
        for (int w = 0; w < 16; ++w) s += sred[w * NCLS + n];
        part[(size_t)(b * NCHUNK + chunk) * NCLS + n] = s;
    }
}

// ---------------------------------------------------------------------------
__global__ __launch_bounds__(256) void k_finish(
    const float* __restrict__ part, const float* __restrict__ bias,
    float* __restrict__ out)
{
    int t = threadIdx.x;
    if (t < BATCH * NCLS) {
        int b = t / NCLS, cls = t % NCLS;
        float s = bias[cls];
        #pragma unroll
        for (int ch = 0; ch < NCHUNK; ++ch)
            s += part[(size_t)(b * NCHUNK + ch) * NCLS + cls];
        out[t] = s;
    }
}

// ---------------------------------------------------------------------------
extern "C" void kernel_launch(void* const* d_in, const int* in_sizes, int n_in,
                              void* d_out, int out_size, void* d_ws, size_t ws_size,
                              hipStream_t stream) {
    const float* data = (const float*)d_in[0];
    const float* fW1  = (const float*)d_in[1];
    const float* fb1  = (const float*)d_in[2];
    const float* fW2  = (const float*)d_in[3];
    const float* fb2  = (const float*)d_in[4];
    const float* fWf  = (const float*)d_in[5];
    const float* fbf  = (const float*)d_in[6];
    float* out = (float*)d_out;

    float* ws   = (float*)d_ws;
    float* Wsp  = ws;                                         // NW*B*NVEC*WPAD = 1,966,080 f
    float* part = Wsp + (size_t)NW * BATCH * NVEC * WPAD;     // B*NCHUNK*NCLS = 2,560 f

    k_weights<<<dim3(NVEC / NROW, NW), 128, 0, stream>>>(
        data, fW1, fb1, fW2, fb2, Wsp);
    k_chain<<<dim3(NCHUNK * BATCH), 512, 0, stream>>>(data, Wsp, fWf, part);
    k_finish<<<dim3(1), 256, 0, stream>>>(part, fbf, out);
}